// Round 1
// baseline (146.284 us; speedup 1.0000x reference)
//
#include <hip/hip_runtime.h>
#include <hip/hip_bf16.h>

#define B_ 8
#define N_ 1024
#define FIN_ 256
#define H_ 8
#define F_ 64
#define HF_ 512
#define BN_ 8192
#define NEG_SLOPE_ 0.2f

using bf16x8 = __attribute__((ext_vector_type(8))) short;
using f32x4  = __attribute__((ext_vector_type(4))) float;
using i32x4  = __attribute__((ext_vector_type(4))) int;

__device__ __forceinline__ short f2bf(float x) {
  union { float f; unsigned u; } v; v.f = x;
  unsigned r = v.u + 0x7fffu + ((v.u >> 16) & 1u);  // RNE
  return (short)(r >> 16);
}

// K0: Wt[f][c] = bf16(W[c][f])   (W is [FIN][H*F] f32)
__global__ void k_wt(const float* __restrict__ W, short* __restrict__ Wt) {
  int idx = blockIdx.x * 256 + threadIdx.x;   // 512*256 elements
  int f = idx >> 8, c = idx & 255;
  Wt[f * FIN_ + c] = f2bf(W[c * HF_ + f]);
}

// K1: h_t = (x@W)^T as bf16 [512][8192]; el_t/er_t [8][8192] f32 fused epilogue.
// D-tile = h^T[64 f x 64 n]; A = Wt (f x k), B = x^T (k x n). One wave per 16-f frag.
__global__ __launch_bounds__(256) void k_h(
    const short* __restrict__ Wt, const float* __restrict__ x,
    const float* __restrict__ aL, const float* __restrict__ aR,
    short* __restrict__ h_t, float* __restrict__ el_t, float* __restrict__ er_t) {
  const int nt = blockIdx.x;       // 128 n-tiles of 64
  const int h  = blockIdx.y;       // 8 heads = 64-f tiles
  const int w  = threadIdx.x >> 6; // wave -> f-frag
  const int l  = threadIdx.x & 63;
  const int lr = l & 15, lk = l >> 4;
  const int n0 = nt * 64;
  const int fbase = h * 64 + w * 16;

  f32x4 acc[4] = {};
  const short* arow = Wt + (fbase + lr) * FIN_ + lk * 8;

#pragma unroll
  for (int k0 = 0; k0 < FIN_; k0 += 32) {
    bf16x8 a = *(const bf16x8*)(arow + k0);
#pragma unroll
    for (int nf = 0; nf < 4; nf++) {
      const float* bp = x + (size_t)(n0 + nf * 16 + lr) * FIN_ + k0 + lk * 8;
      f32x4 b0 = *(const f32x4*)bp;
      f32x4 b1 = *(const f32x4*)(bp + 4);
      bf16x8 bb;
      bb[0]=f2bf(b0[0]); bb[1]=f2bf(b0[1]); bb[2]=f2bf(b0[2]); bb[3]=f2bf(b0[3]);
      bb[4]=f2bf(b1[0]); bb[5]=f2bf(b1[1]); bb[6]=f2bf(b1[2]); bb[7]=f2bf(b1[3]);
      acc[nf] = __builtin_amdgcn_mfma_f32_16x16x32_bf16(a, bb, acc[nf], 0, 0, 0);
    }
  }

  __shared__ float sEl[4][64], sEr[4][64];
  float al[4], ar[4];
#pragma unroll
  for (int r = 0; r < 4; r++) {
    int fl = w * 16 + lk * 4 + r;          // f within head
    al[r] = aL[h * F_ + fl];
    ar[r] = aR[h * F_ + fl];
  }
#pragma unroll
  for (int nf = 0; nf < 4; nf++) {
    int n = n0 + nf * 16 + lr;
#pragma unroll
    for (int r = 0; r < 4; r++)
      h_t[(size_t)(fbase + lk * 4 + r) * BN_ + n] = f2bf(acc[nf][r]);
    float pl = acc[nf][0]*al[0] + acc[nf][1]*al[1] + acc[nf][2]*al[2] + acc[nf][3]*al[3];
    float pr = acc[nf][0]*ar[0] + acc[nf][1]*ar[1] + acc[nf][2]*ar[2] + acc[nf][3]*ar[3];
    pl += __shfl_xor(pl, 16); pl += __shfl_xor(pl, 32);
    pr += __shfl_xor(pr, 16); pr += __shfl_xor(pr, 32);
    if (lk == 0) { sEl[w][nf * 16 + lr] = pl; sEr[w][nf * 16 + lr] = pr; }
  }
  __syncthreads();
  if (threadIdx.x < 64) {
    int n = threadIdx.x;
    el_t[h * BN_ + n0 + n] = sEl[0][n] + sEl[1][n] + sEl[2][n] + sEl[3][n];
    er_t[h * BN_ + n0 + n] = sEr[0][n] + sEr[1][n] + sEr[2][n] + sEr[3][n];
  }
}

// K2: flash-style fused attention. Block = (b, 32-row i-tile); wave = head.
// Swapped PV: D^T[f][i] = h^T(f x j) * alpha^T(j x i); softmax state lane-local (col i = lane&15).
__global__ __launch_bounds__(512) void k_attn(
    const short* __restrict__ h_t, const float* __restrict__ el_t,
    const float* __restrict__ er_t, const float* __restrict__ prior,
    const int* __restrict__ mask, const float* __restrict__ esp,
    float* __restrict__ out) {
  const int b  = blockIdx.x >> 5;
  const int it = blockIdx.x & 31;
  const int h  = threadIdx.x >> 6;
  const int l  = threadIdx.x & 63;
  const int lr = l & 15, lk = l >> 4;
  const float es = *esp;
  const int i0 = it * 32;
  const size_t bn = (size_t)b * N_;

  const float* elh = el_t + h * BN_ + bn;
  const float* erh = er_t + h * BN_ + bn;
  float el[2] = { elh[i0 + lr], elh[i0 + 16 + lr] };

  f32x4 acc[4][2] = {};
  float m[2]    = {-1e30f, -1e30f};
  float lsum[2] = {0.f, 0.f};

  const float* priorB = prior + (size_t)b * N_ * N_;
  const int*   maskB  = mask  + (size_t)b * N_ * N_;

  for (int j0 = 0; j0 < N_; j0 += 32) {
    const int jc = j0 + lk * 8;
    f32x4 er0 = *(const f32x4*)(erh + jc);
    f32x4 er1 = *(const f32x4*)(erh + jc + 4);

    bf16x8 pfrag[2];
    float scale[2];
#pragma unroll
    for (int fi = 0; fi < 2; fi++) {
      const int irow = i0 + fi * 16 + lr;
      const float* pp = priorB + (size_t)irow * N_ + jc;
      const int*   mp = maskB  + (size_t)irow * N_ + jc;
      f32x4 p0 = *(const f32x4*)pp;
      f32x4 p1 = *(const f32x4*)(pp + 4);
      i32x4 k0 = *(const i32x4*)mp;
      i32x4 k1 = *(const i32x4*)(mp + 4);
      float e[8];
#pragma unroll
      for (int t = 0; t < 4; t++) {
        float s = el[fi] + er0[t];
        s = s >= 0.f ? s : NEG_SLOPE_ * s;
        s = fmaf(es, p0[t], s);
        e[t] = (k0[t] != 0) ? s : -1e30f;
        float s2 = el[fi] + er1[t];
        s2 = s2 >= 0.f ? s2 : NEG_SLOPE_ * s2;
        s2 = fmaf(es, p1[t], s2);
        e[t + 4] = (k1[t] != 0) ? s2 : -1e30f;
      }
      float tm = fmaxf(fmaxf(fmaxf(e[0], e[1]), fmaxf(e[2], e[3])),
                       fmaxf(fmaxf(e[4], e[5]), fmaxf(e[6], e[7])));
      tm = fmaxf(tm, __shfl_xor(tm, 16));
      tm = fmaxf(tm, __shfl_xor(tm, 32));
      const float mnew = fmaxf(m[fi], tm);
      const float sc = __expf(m[fi] - mnew);
      float psum = 0.f;
#pragma unroll
      for (int t = 0; t < 8; t++) {
        float p = __expf(e[t] - mnew);
        pfrag[fi][t] = f2bf(p);
        psum += p;
      }
      psum += __shfl_xor(psum, 16);
      psum += __shfl_xor(psum, 32);
      lsum[fi] = lsum[fi] * sc + psum;
      m[fi] = mnew;
      scale[fi] = sc;
    }
#pragma unroll
    for (int ff = 0; ff < 4; ff++)
#pragma unroll
      for (int fi = 0; fi < 2; fi++) {
        acc[ff][fi][0] *= scale[fi];
        acc[ff][fi][1] *= scale[fi];
        acc[ff][fi][2] *= scale[fi];
        acc[ff][fi][3] *= scale[fi];
      }
    const short* hB = h_t + (size_t)(h * 64 + lr) * BN_ + bn + j0 + lk * 8;
#pragma unroll
    for (int ff = 0; ff < 4; ff++) {
      bf16x8 a = *(const bf16x8*)(hB + (size_t)(ff * 16) * BN_);
      acc[ff][0] = __builtin_amdgcn_mfma_f32_16x16x32_bf16(a, pfrag[0], acc[ff][0], 0, 0, 0);
      acc[ff][1] = __builtin_amdgcn_mfma_f32_16x16x32_bf16(a, pfrag[1], acc[ff][1], 0, 0, 0);
    }
  }

#pragma unroll
  for (int fi = 0; fi < 2; fi++) {
    const float inv = 1.0f / lsum[fi];
    const size_t row = bn + i0 + fi * 16 + lr;
#pragma unroll
    for (int ff = 0; ff < 4; ff++) {
      f32x4 v;
      v[0] = acc[ff][fi][0] * inv; v[1] = acc[ff][fi][1] * inv;
      v[2] = acc[ff][fi][2] * inv; v[3] = acc[ff][fi][3] * inv;
      *(f32x4*)(out + row * HF_ + h * 64 + ff * 16 + lk * 4) = v;
    }
  }
}

extern "C" void kernel_launch(void* const* d_in, const int* in_sizes, int n_in,
                              void* d_out, int out_size, void* d_ws, size_t ws_size,
                              hipStream_t stream) {
  const float* x     = (const float*)d_in[0];
  const int*   adj   = (const int*)  d_in[1];
  const float* prior = (const float*)d_in[2];
  const float* W     = (const float*)d_in[3];
  const float* aL    = (const float*)d_in[4];
  const float* aR    = (const float*)d_in[5];
  const float* es    = (const float*)d_in[6];
  float* out = (float*)d_out;

  char* ws = (char*)d_ws;
  short* h_t  = (short*)ws;                               // 512*8192*2 = 8 MB
  short* Wt   = (short*)(ws + 8u * 1024 * 1024);          // 256 KB
  float* el_t = (float*)(ws + 8u * 1024 * 1024 + 256 * 1024);
  float* er_t = (float*)(ws + 8u * 1024 * 1024 + 512 * 1024);

  hipLaunchKernelGGL(k_wt, dim3(512), dim3(256), 0, stream, W, Wt);
  hipLaunchKernelGGL(k_h, dim3(128, 8), dim3(256), 0, stream,
                     Wt, x, aL, aR, h_t, el_t, er_t);
  hipLaunchKernelGGL(k_attn, dim3(256), dim3(512), 0, stream,
                     h_t, el_t, er_t, prior, adj, es, out);
}